// Round 8
// baseline (600.775 us; speedup 1.0000x reference)
//
#include <hip/hip_runtime.h>

#define BB 256
#define HH 1024
#define MM 256
#define HS 128
#define NH 129  // HS+1

typedef __attribute__((ext_vector_type(8))) short short8;
typedef __attribute__((ext_vector_type(4))) float float4v;

__device__ __forceinline__ float sigmoidf_(float x) { return 1.0f / (1.0f + expf(-x)); }
__device__ __forceinline__ float gumbelf_(float u) { return -logf(1e-20f - logf(1e-20f + u)); }

__device__ __forceinline__ unsigned short f2bf(float x) {
    union { float f; unsigned u; } c; c.f = x;
    unsigned u = c.u;
    return (unsigned short)((u + 0x7FFFu + ((u >> 16) & 1u)) >> 16);
}

// 4-row batched scoring: issues 16 loads, 4 dots, 4 interleaved butterflies.
// Per-row arithmetic order identical to the serial version (bitwise-same scores).
__device__ __forceinline__ void score4(const float* __restrict__ r0,
                                       const float* __restrict__ r1,
                                       const float* __restrict__ r2,
                                       const float* __restrict__ r3,
                                       const float4* rv, int lane,
                                       float cb, float hf,
                                       const float* __restrict__ last_usage,
                                       const float* __restrict__ u,
                                       float* __restrict__ sg_out, int mb) {
    float4 a0[4], a1[4], a2[4], a3[4];
#pragma unroll
    for (int it = 0; it < 4; ++it) {
        a0[it] = *(const float4*)(r0 + it * 256 + lane * 4);
        a1[it] = *(const float4*)(r1 + it * 256 + lane * 4);
        a2[it] = *(const float4*)(r2 + it * 256 + lane * 4);
        a3[it] = *(const float4*)(r3 + it * 256 + lane * 4);
    }
    float p0 = 0.f, p1 = 0.f, p2 = 0.f, p3 = 0.f;
#pragma unroll
    for (int it = 0; it < 4; ++it) {
        p0 += a0[it].x * rv[it].x + a0[it].y * rv[it].y + a0[it].z * rv[it].z + a0[it].w * rv[it].w;
        p1 += a1[it].x * rv[it].x + a1[it].y * rv[it].y + a1[it].z * rv[it].z + a1[it].w * rv[it].w;
        p2 += a2[it].x * rv[it].x + a2[it].y * rv[it].y + a2[it].z * rv[it].z + a2[it].w * rv[it].w;
        p3 += a3[it].x * rv[it].x + a3[it].y * rv[it].y + a3[it].z * rv[it].z + a3[it].w * rv[it].w;
    }
#pragma unroll
    for (int off = 32; off > 0; off >>= 1) {
        p0 += __shfl_down(p0, off, 64);
        p1 += __shfl_down(p1, off, 64);
        p2 += __shfl_down(p2, off, 64);
        p3 += __shfl_down(p3, off, 64);
    }
    if (lane == 0) {
        sg_out[mb + 0] = p0 + cb + hf * sigmoidf_(last_usage[mb + 0]) + gumbelf_(u[mb + 0]);
        sg_out[mb + 1] = p1 + cb + hf * sigmoidf_(last_usage[mb + 1]) + gumbelf_(u[mb + 1]);
        sg_out[mb + 2] = p2 + cb + hf * sigmoidf_(last_usage[mb + 2]) + gumbelf_(u[mb + 2]);
        sg_out[mb + 3] = p3 + cb + hf * sigmoidf_(last_usage[mb + 3]) + gumbelf_(u[mb + 3]);
    }
}

// ---------------------------------------------------------------- L1: score1 (bx<256, 16 waves) + weight cvt (bx>=256, 4 tiles/block)
__global__ __launch_bounds__(1024) void k_score1cvt(const float* __restrict__ input_,
                                                    const float* __restrict__ h0,
                                                    const float* __restrict__ W_im,
                                                    const float* __restrict__ W_hm,
                                                    const float* __restrict__ fc1_w,
                                                    const float* __restrict__ fc1_b,
                                                    const float* __restrict__ mem,
                                                    const float* __restrict__ last_usage,
                                                    const float* __restrict__ u1,
                                                    const float* __restrict__ W_ih,
                                                    const float* __restrict__ W_hh,
                                                    const float* __restrict__ W_rh,
                                                    const float* __restrict__ W_s1,
                                                    const float* __restrict__ W_s2,
                                                    const float* __restrict__ W_s3,
                                                    unsigned short* __restrict__ Abf,
                                                    unsigned short* __restrict__ WtG,
                                                    unsigned short* __restrict__ WtS,
                                                    float* __restrict__ sg_out) {
    __shared__ __align__(16) unsigned char smem[33792];
    int bx = blockIdx.x, t = threadIdx.x;
    if (bx >= 256) {
        // ---- weight convert/transpose: 4 tiles per block, one per 256-thread subgroup
        int sub = t >> 8, tloc = t & 255;
        unsigned short (*T)[66] = (unsigned short (*)[66])(smem + sub * 8448);
        int tile = (bx - 256) * 4 + sub;   // 0..3071
        const float* src;
        unsigned short* dst;
        int k0, n0, sstr, dstr, krel;
        if (tile < 2304) {
            int kt = tile / 48, nt = tile % 48;
            k0 = kt * 64; n0 = nt * 64;
            src = (k0 < 1024) ? W_ih : (k0 < 2048) ? W_hh : W_rh;
            krel = k0 & 1023;
            dst = WtG; sstr = 3072; dstr = 3072;
        } else {
            int r = tile - 2304;
            int seg = r >> 8;
            int rem = r & 255;
            int kt = rem >> 4, nt = rem & 15;
            k0 = kt * 64; n0 = nt * 64;
            src = (seg == 0) ? W_s1 : (seg == 1) ? W_s2 : W_s3;
            krel = k0;
            dst = WtS + (size_t)seg * 1048576; sstr = 1024; dstr = 1024;
        }
        for (int i = 0; i < 4; ++i) {
            int e = i * 256 + tloc;
            int kk = e >> 4, nn0 = (e & 15) * 4;
            float4 v = *(const float4*)(src + (size_t)(krel + kk) * sstr + n0 + nn0);
            T[nn0 + 0][kk] = f2bf(v.x);
            T[nn0 + 1][kk] = f2bf(v.y);
            T[nn0 + 2][kk] = f2bf(v.z);
            T[nn0 + 3][kk] = f2bf(v.w);
        }
        __syncthreads();
        for (int i = 0; i < 8; ++i) {
            int e = i * 256 + tloc;
            int nn = e >> 5, kk2 = (e & 31) * 2;
            unsigned val = (unsigned)T[nn][kk2] | ((unsigned)T[nn][kk2 + 1] << 16);
            *(unsigned*)(dst + (size_t)(n0 + nn) * dstr + k0 + kk2) = val;
        }
        return;
    }
    // ---- score pass 1 (1024 threads, 16 waves)
    float* sx = (float*)smem;              // 1024
    float* sh = sx + 1024;                 // 1024
    float* sv = sh + 1024;                 // 1024
    float* red = sv + 1024;                // 8*128
    float* red2 = red + 1024;              // 8
    float* sj = red2 + 8;                  // 129
    float* scb = sj + 129;                 // 1
    int b = bx;
    if (t < 256) {
        float4 v = *(const float4*)(input_ + (size_t)b * HH + t * 4);
        *(float4*)(sx + t * 4) = v;
        ushort4 o; o.x = f2bf(v.x); o.y = f2bf(v.y); o.z = f2bf(v.z); o.w = f2bf(v.w);
        *(ushort4*)(Abf + (size_t)b * 3072 + t * 4) = o;
    } else if (t < 512) {
        int tt = t - 256;
        float4 v = *(const float4*)(h0 + (size_t)b * HH + tt * 4);
        *(float4*)(sh + tt * 4) = v;
        ushort4 o; o.x = f2bf(v.x); o.y = f2bf(v.y); o.z = f2bf(v.z); o.w = f2bf(v.w);
        *(ushort4*)(Abf + (size_t)b * 3072 + 1024 + tt * 4) = o;
    }
    __syncthreads();
    {   // read_head GEMV: j = t&127, 8-way K-split
        int j = t & 127, ks = t >> 7;
        int hb = ks * 128;
        float p = 0.f;
#pragma unroll 8
        for (int h = hb; h < hb + 128; ++h)
            p += sx[h] * W_im[h * NH + j] + sh[h] * W_hm[h * NH + j];
        red[ks * 128 + j] = p;
        if (t >= 1016) {  // j = 128 extra slices
            int k2 = t - 1016;
            int hb2 = k2 * 128;
            float q = 0.f;
#pragma unroll 8
            for (int h = hb2; h < hb2 + 128; ++h)
                q += sx[h] * W_im[h * NH + 128] + sh[h] * W_hm[h * NH + 128];
            red2[k2] = q;
        }
    }
    __syncthreads();
    if (t < 128) {
        float s = 0.f;
        for (int k = 0; k < 8; ++k) s += red[k * 128 + t];
        sj[t] = tanhf(s);
    } else if (t == 128) {
        float s = 0.f;
        for (int k = 0; k < 8; ++k) s += red2[k];
        sj[128] = tanhf(s);
    }
    __syncthreads();
    {   // v projection
        float acc = 0.f;
#pragma unroll 4
        for (int j = 0; j < HS; ++j) acc += sj[j] * fc1_w[(size_t)j * HH + t];
        sv[t] = acc;
    }
    if (t < 64) {
        float p = sj[t] * fc1_b[t] + sj[t + 64] * fc1_b[t + 64];
        for (int off = 32; off > 0; off >>= 1) p += __shfl_down(p, off, 64);
        if (t == 0) *scb = p;
    }
    __syncthreads();
    float cb = *scb, hf = sj[128];
    int wave = t >> 6, lane = t & 63;
    float4 rv[4];
#pragma unroll
    for (int it = 0; it < 4; ++it) rv[it] = *(const float4*)(sv + it * 256 + lane * 4);
    const float* hrow = h0 + (size_t)b * HH;
    const float* mbase = mem + (size_t)b * MM * HH;
    for (int i0 = 0; i0 < 16; i0 += 4) {
        int mrow = wave * 16 + i0;
        const float* r0 = (mrow == 0) ? hrow : (mbase + (size_t)mrow * HH);
        const float* r1 = mbase + (size_t)(mrow + 1) * HH;
        const float* r2 = mbase + (size_t)(mrow + 2) * HH;
        const float* r3 = mbase + (size_t)(mrow + 3) * HH;
        score4(r0, r1, r2, r3, rv, lane, cb, hf, last_usage, u1, sg_out, b * MM + mrow);
    }
}

// ---------------------------------------------------------------- L2: sel1+head1+scores pass 2
__global__ __launch_bounds__(1024) void k_sel_score2(const float* __restrict__ sg1,
                                                     const float* __restrict__ mem,
                                                     const float* __restrict__ h0,
                                                     const float* __restrict__ input_,
                                                     const float* __restrict__ W_im1,
                                                     const float* __restrict__ W_hm1,
                                                     const float* __restrict__ W_mm1,
                                                     const float* __restrict__ bias_m1,
                                                     const float* __restrict__ fc1_w,
                                                     const float* __restrict__ fc1_b,
                                                     const float* __restrict__ last_usage,
                                                     const float* __restrict__ u2,
                                                     unsigned short* __restrict__ Abf,
                                                     float* __restrict__ sg_out) {
    __shared__ float svals[256];
    __shared__ int sidx[256];
    __shared__ float sx[HH], sh[HH], se[HH], sv[HH];
    __shared__ float red[8][128];
    __shared__ float red2[8];
    __shared__ float sj[NH];
    __shared__ float scb;
    int b = blockIdx.x, t = threadIdx.x;
    if (t < 256) {
        svals[t] = sg1[b * MM + t];
        sidx[t] = t;
    }
    __syncthreads();
    for (int s = 128; s > 0; s >>= 1) {
        if (t < s) {
            if (svals[t + s] > svals[t]) { svals[t] = svals[t + s]; sidx[t] = sidx[t + s]; }
        }
        __syncthreads();
    }
    int mstar = sidx[0];
    const float* erow = (mstar == 0) ? (h0 + (size_t)b * HH) : (mem + ((size_t)(b * MM + mstar)) * HH);
    if (t < 256) {
        float4 v = *(const float4*)(erow + t * 4);
        *(float4*)(se + t * 4) = v;
        ushort4 o; o.x = f2bf(v.x); o.y = f2bf(v.y); o.z = f2bf(v.z); o.w = f2bf(v.w);
        *(ushort4*)(Abf + (size_t)b * 3072 + 2048 + t * 4) = o;
    } else if (t < 512) {
        int tt = t - 256;
        *(float4*)(sx + tt * 4) = *(const float4*)(input_ + (size_t)b * HH + tt * 4);
    } else if (t < 768) {
        int tt = t - 512;
        *(float4*)(sh + tt * 4) = *(const float4*)(h0 + (size_t)b * HH + tt * 4);
    }
    __syncthreads();
    {
        int j = t & 127, ks = t >> 7;
        int hb = ks * 128;
        float p = 0.f;
#pragma unroll 4
        for (int h = hb; h < hb + 128; ++h)
            p += sx[h] * W_im1[h * NH + j] + sh[h] * W_hm1[h * NH + j] + se[h] * W_mm1[h * NH + j];
        red[ks][j] = p;
        if (t >= 1016) {
            int k2 = t - 1016;
            int hb2 = k2 * 128;
            float q = 0.f;
#pragma unroll 4
            for (int h = hb2; h < hb2 + 128; ++h)
                q += sx[h] * W_im1[h * NH + 128] + sh[h] * W_hm1[h * NH + 128] + se[h] * W_mm1[h * NH + 128];
            red2[k2] = q;
        }
    }
    __syncthreads();
    if (t < 128) {
        float s = bias_m1[t];
        for (int k = 0; k < 8; ++k) s += red[k][t];
        sj[t] = tanhf(s);
    } else if (t == 128) {
        float s = bias_m1[128];
        for (int k = 0; k < 8; ++k) s += red2[k];
        sj[128] = tanhf(s);
    }
    __syncthreads();
    {
        float acc = 0.f;
#pragma unroll 4
        for (int j = 0; j < HS; ++j) acc += sj[j] * fc1_w[(size_t)j * HH + t];
        sv[t] = acc;
    }
    if (t < 64) {
        float p = sj[t] * fc1_b[t] + sj[t + 64] * fc1_b[t + 64];
        for (int off = 32; off > 0; off >>= 1) p += __shfl_down(p, off, 64);
        if (t == 0) scb = p;
    }
    __syncthreads();
    float cb = scb, hf = sj[128];
    int wave = t >> 6, lane = t & 63;
    float4 rv[4];
#pragma unroll
    for (int it = 0; it < 4; ++it) rv[it] = *(const float4*)(sv + it * 256 + lane * 4);
    const float* hrow = h0 + (size_t)b * HH;
    const float* mbase = mem + (size_t)b * MM * HH;
    for (int i0 = 0; i0 < 16; i0 += 4) {
        int mrow = wave * 16 + i0;
        const float* r0 = (mrow == 0) ? hrow : (mbase + (size_t)mrow * HH);
        const float* r1 = mbase + (size_t)(mrow + 1) * HH;
        const float* r2 = mbase + (size_t)(mrow + 2) * HH;
        const float* r3 = mbase + (size_t)(mrow + 3) * HH;
        score4(r0, r1, r2, r3, rv, lane, cb, hf, last_usage, u2, sg_out, b * MM + mrow);
    }
}

// ---------------------------------------------------------------- L3: MFMA GEMM (all 192 units, split-K 512)
__global__ __launch_bounds__(256) void k_gemm(const unsigned short* __restrict__ Abf,
                                              const unsigned short* __restrict__ WtG,
                                              const unsigned short* __restrict__ WtS,
                                              float* __restrict__ wbp,
                                              float* __restrict__ Sp) {
    __shared__ unsigned short As[128 * 72];
    __shared__ unsigned short Bs[128 * 72];
    int bx = blockIdx.x;
    int mtile = bx & 1, unit = bx >> 1;
    int m0 = mtile * 128;
    const unsigned short* Bp;
    const unsigned short* Ap;
    float* pout;
    int bstr, ncol0;
    if (unit < 144) {
        int nt = unit % 24;
        int kidx = unit / 24;          // 0..5
        int ksel = kidx >> 1, khalf = kidx & 1;
        ncol0 = nt * 128;
        Bp = WtG + (size_t)ncol0 * 3072 + ksel * 1024 + khalf * 512;
        bstr = 3072;
        Ap = Abf + ksel * 1024 + khalf * 512;
        pout = wbp + (size_t)kidx * 786432;
    } else {
        int su = unit - 144;           // 0..47
        int seg = su / 16;
        int rem = su % 16;
        int khalf = rem >> 3, nts = rem & 7;
        ncol0 = seg * 1024 + nts * 128;
        Bp = WtS + (size_t)seg * 1048576 + (size_t)(nts * 128) * 1024 + khalf * 512;
        bstr = 1024;
        Ap = Abf + seg * 1024 + khalf * 512;
        pout = Sp + (size_t)khalf * 786432;
    }

    int tid = threadIdx.x;
    int wave = tid >> 6, lane = tid & 63;
    int wm = wave >> 1, wn = wave & 1;
    int q = lane >> 4, lm = lane & 15;

    float4v acc[4][4];
    for (int i = 0; i < 4; ++i)
        for (int j = 0; j < 4; ++j)
            acc[i][j] = (float4v){0.f, 0.f, 0.f, 0.f};

    for (int kt = 0; kt < 512; kt += 64) {
        for (int rr = 0; rr < 4; ++rr) {
            int e = rr * 256 + tid;
            int row = e >> 3, cg = e & 7;
            *(uint4*)&As[row * 72 + cg * 8] =
                *(const uint4*)(Ap + (size_t)(m0 + row) * 3072 + kt + cg * 8);
            *(uint4*)&Bs[row * 72 + cg * 8] =
                *(const uint4*)(Bp + (size_t)row * bstr + kt + cg * 8);
        }
        __syncthreads();
        for (int ks = 0; ks < 64; ks += 32) {
            short8 av[4], bv[4];
            for (int i = 0; i < 4; ++i)
                av[i] = *(const short8*)&As[(wm * 64 + i * 16 + lm) * 72 + ks + q * 8];
            for (int j = 0; j < 4; ++j)
                bv[j] = *(const short8*)&Bs[(wn * 64 + j * 16 + lm) * 72 + ks + q * 8];
            for (int i = 0; i < 4; ++i)
                for (int j = 0; j < 4; ++j)
                    acc[i][j] = __builtin_amdgcn_mfma_f32_16x16x32_bf16(av[i], bv[j], acc[i][j], 0, 0, 0);
        }
        __syncthreads();
    }

    for (int i = 0; i < 4; ++i)
        for (int j = 0; j < 4; ++j) {
            int n = ncol0 + wn * 64 + j * 16 + lm;
            for (int reg = 0; reg < 4; ++reg) {
                int m = m0 + wm * 64 + i * 16 + q * 4 + reg;
                pout[(size_t)m * 3072 + n] = acc[i][j][reg];
            }
        }
}

// ---------------------------------------------------------------- L4: final (fused sel2 + GRU epilogue)
__global__ __launch_bounds__(256) void k_final(const float* __restrict__ sg2,
                                               const float* __restrict__ mem,
                                               const float* __restrict__ wbp,
                                               const float* __restrict__ Sp,
                                               const float* __restrict__ h0,
                                               const float* __restrict__ bias,
                                               const float* __restrict__ b1,
                                               const float* __restrict__ b2,
                                               const float* __restrict__ b3,
                                               float* __restrict__ out) {
    __shared__ float svals[256];
    __shared__ int sidx[256];
    int b = blockIdx.x, t = threadIdx.x;
    svals[t] = sg2[b * MM + t];
    sidx[t] = t;
    __syncthreads();
    for (int s = 128; s > 0; s >>= 1) {
        if (t < s) {
            if (svals[t + s] > svals[t]) { svals[t] = svals[t + s]; sidx[t] = sidx[t + s]; }
        }
        __syncthreads();
    }
    int mstar = sidx[0];
    const float* erow = (mstar == 0) ? (h0 + (size_t)b * HH) : (mem + ((size_t)(b * MM + mstar)) * HH);
    float* o_row = out + (size_t)BB * HH + (size_t)b * 2 * HH;
    {
        int hb = t * 4;
        *(float4*)(o_row + HH + hb) = *(const float4*)(erow + hb);
    }
    int h = t * 4;
    size_t base = (size_t)b * 3072;
    float4 wsum[3];
#pragma unroll
    for (int g = 0; g < 3; ++g) {
        float4 a = make_float4(0.f, 0.f, 0.f, 0.f);
#pragma unroll
        for (int p = 0; p < 6; ++p) {
            float4 w = *(const float4*)(wbp + (size_t)p * 786432 + base + g * 1024 + h);
            a.x += w.x; a.y += w.y; a.z += w.z; a.w += w.w;
        }
        wsum[g] = a;
    }
    float4 bi0 = *(const float4*)(bias + h);
    float4 bi1 = *(const float4*)(bias + 1024 + h);
    float4 bi2 = *(const float4*)(bias + 2048 + h);
    float4 r4 = make_float4(sigmoidf_(wsum[0].x + bi0.x), sigmoidf_(wsum[0].y + bi0.y),
                            sigmoidf_(wsum[0].z + bi0.z), sigmoidf_(wsum[0].w + bi0.w));
    float4 z4 = make_float4(sigmoidf_(wsum[1].x + bi1.x), sigmoidf_(wsum[1].y + bi1.y),
                            sigmoidf_(wsum[1].z + bi1.z), sigmoidf_(wsum[1].w + bi1.w));
    float4 n4 = make_float4(sigmoidf_(wsum[2].x + bi2.x), sigmoidf_(wsum[2].y + bi2.y),
                            sigmoidf_(wsum[2].z + bi2.z), sigmoidf_(wsum[2].w + bi2.w));
    float4 s1, s2, s3;
    {
        float4 a0 = *(const float4*)(Sp + base + h);
        float4 a1 = *(const float4*)(Sp + 786432 + base + h);
        s1 = make_float4(a0.x + a1.x, a0.y + a1.y, a0.z + a1.z, a0.w + a1.w);
        a0 = *(const float4*)(Sp + base + 1024 + h);
        a1 = *(const float4*)(Sp + 786432 + base + 1024 + h);
        s2 = make_float4(a0.x + a1.x, a0.y + a1.y, a0.z + a1.z, a0.w + a1.w);
        a0 = *(const float4*)(Sp + base + 2048 + h);
        a1 = *(const float4*)(Sp + 786432 + base + 2048 + h);
        s3 = make_float4(a0.x + a1.x, a0.y + a1.y, a0.z + a1.z, a0.w + a1.w);
    }
    float4 v1 = *(const float4*)(b1 + h);
    float4 v2 = *(const float4*)(b2 + h);
    float4 v3 = *(const float4*)(b3 + h);
    float4 h0v = *(const float4*)(h0 + (size_t)b * HH + h);
    float4 hn, h1;
    hn.x = tanhf(s1.x + v1.x + r4.x * (s2.x + v2.x) + z4.x * (s3.x + v3.x));
    hn.y = tanhf(s1.y + v1.y + r4.y * (s2.y + v2.y) + z4.y * (s3.y + v3.y));
    hn.z = tanhf(s1.z + v1.z + r4.z * (s2.z + v2.z) + z4.z * (s3.z + v3.z));
    hn.w = tanhf(s1.w + v1.w + r4.w * (s2.w + v2.w) + z4.w * (s3.w + v3.w));
    h1.x = n4.x * hn.x + (1.f - n4.x) * h0v.x;
    h1.y = n4.y * hn.y + (1.f - n4.y) * h0v.y;
    h1.z = n4.z * hn.z + (1.f - n4.z) * h0v.z;
    h1.w = n4.w * hn.w + (1.f - n4.w) * h0v.w;
    *(float4*)(out + (size_t)b * HH + h) = h1;
    *(float4*)(o_row + h) = h1;
}

extern "C" void kernel_launch(void* const* d_in, const int* in_sizes, int n_in,
                              void* d_out, int out_size, void* d_ws, size_t ws_size,
                              hipStream_t stream) {
    const float* input_ = (const float*)d_in[0];
    const float* h0 = (const float*)d_in[1];
    const float* mem = (const float*)d_in[2];
    const float* last_usage = (const float*)d_in[3];
    const float* u1 = (const float*)d_in[4];
    const float* u2 = (const float*)d_in[5];
    const float* W_ih = (const float*)d_in[6];
    const float* W_hh = (const float*)d_in[7];
    const float* W_rh = (const float*)d_in[8];
    const float* W_s1 = (const float*)d_in[9];
    const float* W_s2 = (const float*)d_in[10];
    const float* W_s3 = (const float*)d_in[11];
    const float* bias = (const float*)d_in[12];
    const float* W_im = (const float*)d_in[13];
    const float* W_hm = (const float*)d_in[14];
    const float* fc1_w = (const float*)d_in[15];
    const float* fc1_b = (const float*)d_in[16];
    const float* W_im1 = (const float*)d_in[17];
    const float* W_hm1 = (const float*)d_in[18];
    const float* W_mm1 = (const float*)d_in[19];
    const float* bias_m1 = (const float*)d_in[20];
    const float* bias_1 = (const float*)d_in[21];
    const float* bias_2 = (const float*)d_in[22];
    const float* bias_3 = (const float*)d_in[23];
    float* out = (float*)d_out;

    float* ws = (float*)d_ws;
    float* sg1 = ws;                        // 65536
    float* sg2 = sg1 + 65536;               // 65536
    float* wbp = sg2 + 65536;               // 6 * 786432
    float* Sp = wbp + 6 * 786432;           // 2 * 786432
    unsigned short* Abf = (unsigned short*)(Sp + 2 * 786432);  // 786432 bf16
    unsigned short* WtG = Abf + 786432;     // 9437184 bf16
    unsigned short* WtS = WtG + 9437184;    // 3145728 bf16

    k_score1cvt<<<256 + 768, 1024, 0, stream>>>(input_, h0, W_im, W_hm, fc1_w, fc1_b,
                                                mem, last_usage, u1,
                                                W_ih, W_hh, W_rh, W_s1, W_s2, W_s3,
                                                Abf, WtG, WtS, sg1);
    k_sel_score2<<<BB, 1024, 0, stream>>>(sg1, mem, h0, input_, W_im1, W_hm1, W_mm1, bias_m1,
                                          fc1_w, fc1_b, last_usage, u2, Abf, sg2);
    k_gemm<<<384, 256, 0, stream>>>(Abf, WtG, WtS, wbp, Sp);
    k_final<<<BB, 256, 0, stream>>>(sg2, mem, wbp, Sp, h0, bias, bias_1, bias_2, bias_3, out);
}

// Round 9
// 579.688 us; speedup vs baseline: 1.0364x; 1.0364x over previous
//
#include <hip/hip_runtime.h>

#define BB 256
#define HH 1024
#define MM 256
#define HS 128
#define NH 129  // HS+1

typedef __attribute__((ext_vector_type(8))) short short8;
typedef __attribute__((ext_vector_type(4))) float float4v;

__device__ __forceinline__ float sigmoidf_(float x) { return 1.0f / (1.0f + expf(-x)); }
__device__ __forceinline__ float gumbelf_(float u) { return -logf(1e-20f - logf(1e-20f + u)); }

__device__ __forceinline__ unsigned short f2bf(float x) {
    union { float f; unsigned u; } c; c.f = x;
    unsigned u = c.u;
    return (unsigned short)((u + 0x7FFFu + ((u >> 16) & 1u)) >> 16);
}

// ---------------------------------------------------------------- scoring from P
// 1024 threads: thread handles row m = wave*16 + (lane>>2), j-chunk q4 = lane&3.
// m==0 is overridden by an exact fp32 dot(h0,sv) on wave 15 (bitwise-identical to
// the round-2..8 reduction order).
__device__ __forceinline__ void score_from_P(const float* __restrict__ P,
                                             const float* __restrict__ sj,
                                             const float* __restrict__ sv,
                                             const float* __restrict__ h0row,
                                             float cb, float hf,
                                             const float* __restrict__ last_usage,
                                             const float* __restrict__ u,
                                             float* __restrict__ sg_out,
                                             int b, int t) {
    int wave = t >> 6, lane = t & 63;
    int mrow = wave * 16 + (lane >> 2);
    int q4 = lane & 3;
    const float* Prow = P + ((size_t)b * MM + mrow) * HS + q4 * 32;
    float p = 0.f;
#pragma unroll
    for (int g = 0; g < 8; ++g) {
        float4 pv = *(const float4*)(Prow + g * 4);
        float4 sjv = *(const float4*)(sj + q4 * 32 + g * 4);
        p += pv.x * sjv.x + pv.y * sjv.y + pv.z * sjv.z + pv.w * sjv.w;
    }
    p += __shfl_down(p, 2, 64);
    p += __shfl_down(p, 1, 64);
    if (q4 == 0 && mrow != 0) {
        int mb = b * MM + mrow;
        sg_out[mb] = p + cb + hf * sigmoidf_(last_usage[mb]) + gumbelf_(u[mb]);
    }
    if (wave == 15) {  // exact fp32 row 0 (mem_eff[b,0] = h0)
        float q = 0.f;
#pragma unroll
        for (int it = 0; it < 4; ++it) {
            float4 mv = *(const float4*)(h0row + it * 256 + lane * 4);
            float4 rv = *(const float4*)(sv + it * 256 + lane * 4);
            q += mv.x * rv.x + mv.y * rv.y + mv.z * rv.z + mv.w * rv.w;
        }
        for (int off = 32; off > 0; off >>= 1) q += __shfl_down(q, off, 64);
        if (lane == 0) {
            int mb = b * MM;
            sg_out[mb] = q + cb + hf * sigmoidf_(last_usage[mb]) + gumbelf_(u[mb]);
        }
    }
}

// ---------------------------------------------------------------- L1: P-GEMM (bx<512) + weight cvt (bx>=512)
// P[r][j] = sum_h bf16(mem[r][h]) * bf16(fc1_w[j][h]), r = b*256+m flattened.
__global__ __launch_bounds__(256) void k_pgemm_cvt(const float* __restrict__ mem,
                                                   const float* __restrict__ fc1_w,
                                                   const float* __restrict__ W_ih,
                                                   const float* __restrict__ W_hh,
                                                   const float* __restrict__ W_rh,
                                                   const float* __restrict__ W_s1,
                                                   const float* __restrict__ W_s2,
                                                   const float* __restrict__ W_s3,
                                                   unsigned short* __restrict__ WtG,
                                                   unsigned short* __restrict__ WtS,
                                                   float* __restrict__ P) {
    __shared__ __align__(16) unsigned char smem[73728];
    int bx = blockIdx.x, t = threadIdx.x;
    if (bx >= 512) {
        // ---- weight convert/transpose tile (one 64x64 tile per block)
        unsigned short (*T)[66] = (unsigned short (*)[66])smem;
        int tile = bx - 512;               // 0..3071
        const float* src;
        unsigned short* dst;
        int k0, n0, sstr, dstr, krel;
        if (tile < 2304) {
            int kt = tile / 48, nt = tile % 48;
            k0 = kt * 64; n0 = nt * 64;
            src = (k0 < 1024) ? W_ih : (k0 < 2048) ? W_hh : W_rh;
            krel = k0 & 1023;
            dst = WtG; sstr = 3072; dstr = 3072;
        } else {
            int r = tile - 2304;
            int seg = r >> 8;
            int rem = r & 255;
            int kt = rem >> 4, nt = rem & 15;
            k0 = kt * 64; n0 = nt * 64;
            src = (seg == 0) ? W_s1 : (seg == 1) ? W_s2 : W_s3;
            krel = k0;
            dst = WtS + (size_t)seg * 1048576; sstr = 1024; dstr = 1024;
        }
        for (int i = 0; i < 4; ++i) {
            int e = i * 256 + t;
            int kk = e >> 4, nn0 = (e & 15) * 4;
            float4 v = *(const float4*)(src + (size_t)(krel + kk) * sstr + n0 + nn0);
            T[nn0 + 0][kk] = f2bf(v.x);
            T[nn0 + 1][kk] = f2bf(v.y);
            T[nn0 + 2][kk] = f2bf(v.z);
            T[nn0 + 3][kk] = f2bf(v.w);
        }
        __syncthreads();
        for (int i = 0; i < 8; ++i) {
            int e = i * 256 + t;
            int nn = e >> 5, kk2 = (e & 31) * 2;
            unsigned val = (unsigned)T[nn][kk2] | ((unsigned)T[nn][kk2 + 1] << 16);
            *(unsigned*)(dst + (size_t)(n0 + nn) * dstr + k0 + kk2) = val;
        }
        return;
    }
    // ---- P-GEMM: 128 rows x 128 cols, K = 1024, on-the-fly fp32->bf16
    unsigned short* As = (unsigned short*)smem;          // 128*72
    unsigned short* Bs = As + 128 * 72;                  // 128*72
    int m0 = bx * 128;
    const float* Asrc = mem + (size_t)m0 * 1024;

    int wave = t >> 6, lane = t & 63;
    int wm = wave >> 1, wn = wave & 1;
    int q = lane >> 4, lm = lane & 15;

    float4v acc[4][4];
    for (int i = 0; i < 4; ++i)
        for (int j = 0; j < 4; ++j)
            acc[i][j] = (float4v){0.f, 0.f, 0.f, 0.f};

    for (int kt = 0; kt < 1024; kt += 64) {
        for (int g = 0; g < 4; ++g) {
            int gi = g * 256 + t;          // 0..1023
            int row = gi >> 3, seg = gi & 7;
            const float* sa = Asrc + (size_t)row * 1024 + kt + seg * 8;
            float4 f0 = *(const float4*)sa;
            float4 f1 = *(const float4*)(sa + 4);
            uint4 pk;
            pk.x = (unsigned)f2bf(f0.x) | ((unsigned)f2bf(f0.y) << 16);
            pk.y = (unsigned)f2bf(f0.z) | ((unsigned)f2bf(f0.w) << 16);
            pk.z = (unsigned)f2bf(f1.x) | ((unsigned)f2bf(f1.y) << 16);
            pk.w = (unsigned)f2bf(f1.z) | ((unsigned)f2bf(f1.w) << 16);
            *(uint4*)&As[row * 72 + seg * 8] = pk;
            const float* sb = fc1_w + (size_t)row * 1024 + kt + seg * 8;
            float4 g0 = *(const float4*)sb;
            float4 g1 = *(const float4*)(sb + 4);
            uint4 qk;
            qk.x = (unsigned)f2bf(g0.x) | ((unsigned)f2bf(g0.y) << 16);
            qk.y = (unsigned)f2bf(g0.z) | ((unsigned)f2bf(g0.w) << 16);
            qk.z = (unsigned)f2bf(g1.x) | ((unsigned)f2bf(g1.y) << 16);
            qk.w = (unsigned)f2bf(g1.z) | ((unsigned)f2bf(g1.w) << 16);
            *(uint4*)&Bs[row * 72 + seg * 8] = qk;
        }
        __syncthreads();
        for (int ks = 0; ks < 64; ks += 32) {
            short8 av[4], bv[4];
            for (int i = 0; i < 4; ++i)
                av[i] = *(const short8*)&As[(wm * 64 + i * 16 + lm) * 72 + ks + q * 8];
            for (int j = 0; j < 4; ++j)
                bv[j] = *(const short8*)&Bs[(wn * 64 + j * 16 + lm) * 72 + ks + q * 8];
            for (int i = 0; i < 4; ++i)
                for (int j = 0; j < 4; ++j)
                    acc[i][j] = __builtin_amdgcn_mfma_f32_16x16x32_bf16(av[i], bv[j], acc[i][j], 0, 0, 0);
        }
        __syncthreads();
    }

    for (int i = 0; i < 4; ++i)
        for (int j = 0; j < 4; ++j) {
            int n = wn * 64 + j * 16 + lm;
            for (int reg = 0; reg < 4; ++reg) {
                int m = m0 + wm * 64 + i * 16 + q * 4 + reg;
                P[(size_t)m * HS + n] = acc[i][j][reg];
            }
        }
}

// ---------------------------------------------------------------- L2: heads + project + scores1 (from P)
__global__ __launch_bounds__(1024) void k_score1(const float* __restrict__ input_,
                                                 const float* __restrict__ h0,
                                                 const float* __restrict__ W_im,
                                                 const float* __restrict__ W_hm,
                                                 const float* __restrict__ fc1_w,
                                                 const float* __restrict__ fc1_b,
                                                 const float* __restrict__ P,
                                                 const float* __restrict__ last_usage,
                                                 const float* __restrict__ u1,
                                                 unsigned short* __restrict__ Abf,
                                                 float* __restrict__ sg_out) {
    __shared__ __align__(16) float sx[HH];
    __shared__ __align__(16) float sh[HH];
    __shared__ __align__(16) float sv[HH];
    __shared__ float red[8][128];
    __shared__ float red2[8];
    __shared__ __align__(16) float sj[132];
    __shared__ float scb;
    int b = blockIdx.x, t = threadIdx.x;
    if (t < 256) {
        float4 v = *(const float4*)(input_ + (size_t)b * HH + t * 4);
        *(float4*)(sx + t * 4) = v;
        ushort4 o; o.x = f2bf(v.x); o.y = f2bf(v.y); o.z = f2bf(v.z); o.w = f2bf(v.w);
        *(ushort4*)(Abf + (size_t)b * 3072 + t * 4) = o;
    } else if (t < 512) {
        int tt = t - 256;
        float4 v = *(const float4*)(h0 + (size_t)b * HH + tt * 4);
        *(float4*)(sh + tt * 4) = v;
        ushort4 o; o.x = f2bf(v.x); o.y = f2bf(v.y); o.z = f2bf(v.z); o.w = f2bf(v.w);
        *(ushort4*)(Abf + (size_t)b * 3072 + 1024 + tt * 4) = o;
    }
    __syncthreads();
    {   // read_head GEMV: j = t&127, 8-way K-split
        int j = t & 127, ks = t >> 7;
        int hb = ks * 128;
        float p = 0.f;
#pragma unroll 8
        for (int h = hb; h < hb + 128; ++h)
            p += sx[h] * W_im[h * NH + j] + sh[h] * W_hm[h * NH + j];
        red[ks][j] = p;
        if (t >= 1016) {
            int k2 = t - 1016;
            int hb2 = k2 * 128;
            float q = 0.f;
#pragma unroll 8
            for (int h = hb2; h < hb2 + 128; ++h)
                q += sx[h] * W_im[h * NH + 128] + sh[h] * W_hm[h * NH + 128];
            red2[k2] = q;
        }
    }
    __syncthreads();
    if (t < 128) {
        float s = 0.f;
        for (int k = 0; k < 8; ++k) s += red[k][t];
        sj[t] = tanhf(s);
    } else if (t == 128) {
        float s = 0.f;
        for (int k = 0; k < 8; ++k) s += red2[k];
        sj[128] = tanhf(s);
    }
    __syncthreads();
    {   // v projection
        float acc = 0.f;
#pragma unroll 4
        for (int j = 0; j < HS; ++j) acc += sj[j] * fc1_w[(size_t)j * HH + t];
        sv[t] = acc;
    }
    if (t < 64) {
        float p = sj[t] * fc1_b[t] + sj[t + 64] * fc1_b[t + 64];
        for (int off = 32; off > 0; off >>= 1) p += __shfl_down(p, off, 64);
        if (t == 0) scb = p;
    }
    __syncthreads();
    score_from_P(P, sj, sv, h0 + (size_t)b * HH, scb, sj[128], last_usage, u1, sg_out, b, t);
}

// ---------------------------------------------------------------- L3: sel1 + head1 + scores2 (from P)
__global__ __launch_bounds__(1024) void k_sel_score2(const float* __restrict__ sg1,
                                                     const float* __restrict__ mem,
                                                     const float* __restrict__ h0,
                                                     const float* __restrict__ input_,
                                                     const float* __restrict__ W_im1,
                                                     const float* __restrict__ W_hm1,
                                                     const float* __restrict__ W_mm1,
                                                     const float* __restrict__ bias_m1,
                                                     const float* __restrict__ fc1_w,
                                                     const float* __restrict__ fc1_b,
                                                     const float* __restrict__ P,
                                                     const float* __restrict__ last_usage,
                                                     const float* __restrict__ u2,
                                                     unsigned short* __restrict__ Abf,
                                                     float* __restrict__ sg_out) {
    __shared__ float svals[256];
    __shared__ int sidx[256];
    __shared__ __align__(16) float sx[HH];
    __shared__ __align__(16) float sh[HH];
    __shared__ __align__(16) float se[HH];
    __shared__ __align__(16) float sv[HH];
    __shared__ float red[8][128];
    __shared__ float red2[8];
    __shared__ __align__(16) float sj[132];
    __shared__ float scb;
    int b = blockIdx.x, t = threadIdx.x;
    if (t < 256) {
        svals[t] = sg1[b * MM + t];
        sidx[t] = t;
    }
    __syncthreads();
    for (int s = 128; s > 0; s >>= 1) {
        if (t < s) {
            if (svals[t + s] > svals[t]) { svals[t] = svals[t + s]; sidx[t] = sidx[t + s]; }
        }
        __syncthreads();
    }
    int mstar = sidx[0];
    const float* erow = (mstar == 0) ? (h0 + (size_t)b * HH) : (mem + ((size_t)(b * MM + mstar)) * HH);
    if (t < 256) {
        float4 v = *(const float4*)(erow + t * 4);
        *(float4*)(se + t * 4) = v;
        ushort4 o; o.x = f2bf(v.x); o.y = f2bf(v.y); o.z = f2bf(v.z); o.w = f2bf(v.w);
        *(ushort4*)(Abf + (size_t)b * 3072 + 2048 + t * 4) = o;
    } else if (t < 512) {
        int tt = t - 256;
        *(float4*)(sx + tt * 4) = *(const float4*)(input_ + (size_t)b * HH + tt * 4);
    } else if (t < 768) {
        int tt = t - 512;
        *(float4*)(sh + tt * 4) = *(const float4*)(h0 + (size_t)b * HH + tt * 4);
    }
    __syncthreads();
    {
        int j = t & 127, ks = t >> 7;
        int hb = ks * 128;
        float p = 0.f;
#pragma unroll 4
        for (int h = hb; h < hb + 128; ++h)
            p += sx[h] * W_im1[h * NH + j] + sh[h] * W_hm1[h * NH + j] + se[h] * W_mm1[h * NH + j];
        red[ks][j] = p;
        if (t >= 1016) {
            int k2 = t - 1016;
            int hb2 = k2 * 128;
            float q = 0.f;
#pragma unroll 4
            for (int h = hb2; h < hb2 + 128; ++h)
                q += sx[h] * W_im1[h * NH + 128] + sh[h] * W_hm1[h * NH + 128] + se[h] * W_mm1[h * NH + 128];
            red2[k2] = q;
        }
    }
    __syncthreads();
    if (t < 128) {
        float s = bias_m1[t];
        for (int k = 0; k < 8; ++k) s += red[k][t];
        sj[t] = tanhf(s);
    } else if (t == 128) {
        float s = bias_m1[128];
        for (int k = 0; k < 8; ++k) s += red2[k];
        sj[128] = tanhf(s);
    }
    __syncthreads();
    {
        float acc = 0.f;
#pragma unroll 4
        for (int j = 0; j < HS; ++j) acc += sj[j] * fc1_w[(size_t)j * HH + t];
        sv[t] = acc;
    }
    if (t < 64) {
        float p = sj[t] * fc1_b[t] + sj[t + 64] * fc1_b[t + 64];
        for (int off = 32; off > 0; off >>= 1) p += __shfl_down(p, off, 64);
        if (t == 0) scb = p;
    }
    __syncthreads();
    score_from_P(P, sj, sv, h0 + (size_t)b * HH, scb, sj[128], last_usage, u2, sg_out, b, t);
}

// ---------------------------------------------------------------- L4: MFMA GEMM (all 192 units, split-K 512)
__global__ __launch_bounds__(256) void k_gemm(const unsigned short* __restrict__ Abf,
                                              const unsigned short* __restrict__ WtG,
                                              const unsigned short* __restrict__ WtS,
                                              float* __restrict__ wbp,
                                              float* __restrict__ Sp) {
    __shared__ unsigned short As[128 * 72];
    __shared__ unsigned short Bs[128 * 72];
    int bx = blockIdx.x;
    int mtile = bx & 1, unit = bx >> 1;
    int m0 = mtile * 128;
    const unsigned short* Bp;
    const unsigned short* Ap;
    float* pout;
    int bstr, ncol0;
    if (unit < 144) {
        int nt = unit % 24;
        int kidx = unit / 24;          // 0..5
        int ksel = kidx >> 1, khalf = kidx & 1;
        ncol0 = nt * 128;
        Bp = WtG + (size_t)ncol0 * 3072 + ksel * 1024 + khalf * 512;
        bstr = 3072;
        Ap = Abf + ksel * 1024 + khalf * 512;
        pout = wbp + (size_t)kidx * 786432;
    } else {
        int su = unit - 144;           // 0..47
        int seg = su / 16;
        int rem = su % 16;
        int khalf = rem >> 3, nts = rem & 7;
        ncol0 = seg * 1024 + nts * 128;
        Bp = WtS + (size_t)seg * 1048576 + (size_t)(nts * 128) * 1024 + khalf * 512;
        bstr = 1024;
        Ap = Abf + seg * 1024 + khalf * 512;
        pout = Sp + (size_t)khalf * 786432;
    }

    int tid = threadIdx.x;
    int wave = tid >> 6, lane = tid & 63;
    int wm = wave >> 1, wn = wave & 1;
    int q = lane >> 4, lm = lane & 15;

    float4v acc[4][4];
    for (int i = 0; i < 4; ++i)
        for (int j = 0; j < 4; ++j)
            acc[i][j] = (float4v){0.f, 0.f, 0.f, 0.f};

    for (int kt = 0; kt < 512; kt += 64) {
        for (int rr = 0; rr < 4; ++rr) {
            int e = rr * 256 + tid;
            int row = e >> 3, cg = e & 7;
            *(uint4*)&As[row * 72 + cg * 8] =
                *(const uint4*)(Ap + (size_t)(m0 + row) * 3072 + kt + cg * 8);
            *(uint4*)&Bs[row * 72 + cg * 8] =
                *(const uint4*)(Bp + (size_t)row * bstr + kt + cg * 8);
        }
        __syncthreads();
        for (int ks = 0; ks < 64; ks += 32) {
            short8 av[4], bv[4];
            for (int i = 0; i < 4; ++i)
                av[i] = *(const short8*)&As[(wm * 64 + i * 16 + lm) * 72 + ks + q * 8];
            for (int j = 0; j < 4; ++j)
                bv[j] = *(const short8*)&Bs[(wn * 64 + j * 16 + lm) * 72 + ks + q * 8];
            for (int i = 0; i < 4; ++i)
                for (int j = 0; j < 4; ++j)
                    acc[i][j] = __builtin_amdgcn_mfma_f32_16x16x32_bf16(av[i], bv[j], acc[i][j], 0, 0, 0);
        }
        __syncthreads();
    }

    for (int i = 0; i < 4; ++i)
        for (int j = 0; j < 4; ++j) {
            int n = ncol0 + wn * 64 + j * 16 + lm;
            for (int reg = 0; reg < 4; ++reg) {
                int m = m0 + wm * 64 + i * 16 + q * 4 + reg;
                pout[(size_t)m * 3072 + n] = acc[i][j][reg];
            }
        }
}

// ---------------------------------------------------------------- L5: final (fused sel2 + GRU epilogue)
__global__ __launch_bounds__(256) void k_final(const float* __restrict__ sg2,
                                               const float* __restrict__ mem,
                                               const float* __restrict__ wbp,
                                               const float* __restrict__ Sp,
                                               const float* __restrict__ h0,
                                               const float* __restrict__ bias,
                                               const float* __restrict__ b1,
                                               const float* __restrict__ b2,
                                               const float* __restrict__ b3,
                                               float* __restrict__ out) {
    __shared__ float svals[256];
    __shared__ int sidx[256];
    int b = blockIdx.x, t = threadIdx.x;
    svals[t] = sg2[b * MM + t];
    sidx[t] = t;
    __syncthreads();
    for (int s = 128; s > 0; s >>= 1) {
        if (t < s) {
            if (svals[t + s] > svals[t]) { svals[t] = svals[t + s]; sidx[t] = sidx[t + s]; }
        }
        __syncthreads();
    }
    int mstar = sidx[0];
    const float* erow = (mstar == 0) ? (h0 + (size_t)b * HH) : (mem + ((size_t)(b * MM + mstar)) * HH);
    float* o_row = out + (size_t)BB * HH + (size_t)b * 2 * HH;
    {
        int hb = t * 4;
        *(float4*)(o_row + HH + hb) = *(const float4*)(erow + hb);
    }
    int h = t * 4;
    size_t base = (size_t)b * 3072;
    float4 wsum[3];
#pragma unroll
    for (int g = 0; g < 3; ++g) {
        float4 a = make_float4(0.f, 0.f, 0.f, 0.f);
#pragma unroll
        for (int p = 0; p < 6; ++p) {
            float4 w = *(const float4*)(wbp + (size_t)p * 786432 + base + g * 1024 + h);
            a.x += w.x; a.y += w.y; a.z += w.z; a.w += w.w;
        }
        wsum[g] = a;
    }
    float4 bi0 = *(const float4*)(bias + h);
    float4 bi1 = *(const float4*)(bias + 1024 + h);
    float4 bi2 = *(const float4*)(bias + 2048 + h);
    float4 r4 = make_float4(sigmoidf_(wsum[0].x + bi0.x), sigmoidf_(wsum[0].y + bi0.y),
                            sigmoidf_(wsum[0].z + bi0.z), sigmoidf_(wsum[0].w + bi0.w));
    float4 z4 = make_float4(sigmoidf_(wsum[1].x + bi1.x), sigmoidf_(wsum[1].y + bi1.y),
                            sigmoidf_(wsum[1].z + bi1.z), sigmoidf_(wsum[1].w + bi1.w));
    float4 n4 = make_float4(sigmoidf_(wsum[2].x + bi2.x), sigmoidf_(wsum[2].y + bi2.y),
                            sigmoidf_(wsum[2].z + bi2.z), sigmoidf_(wsum[2].w + bi2.w));
    float4 s1, s2, s3;
    {
        float4 a0 = *(const float4*)(Sp + base + h);
        float4 a1 = *(const float4*)(Sp + 786432 + base + h);
        s1 = make_float4(a0.x + a1.x, a0.y + a1.y, a0.z + a1.z, a0.w + a1.w);
        a0 = *(const float4*)(Sp + base + 1024 + h);
        a1 = *(const float4*)(Sp + 786432 + base + 1024 + h);
        s2 = make_float4(a0.x + a1.x, a0.y + a1.y, a0.z + a1.z, a0.w + a1.w);
        a0 = *(const float4*)(Sp + base + 2048 + h);
        a1 = *(const float4*)(Sp + 786432 + base + 2048 + h);
        s3 = make_float4(a0.x + a1.x, a0.y + a1.y, a0.z + a1.z, a0.w + a1.w);
    }
    float4 v1 = *(const float4*)(b1 + h);
    float4 v2 = *(const float4*)(b2 + h);
    float4 v3 = *(const float4*)(b3 + h);
    float4 h0v = *(const float4*)(h0 + (size_t)b * HH + h);
    float4 hn, h1;
    hn.x = tanhf(s1.x + v1.x + r4.x * (s2.x + v2.x) + z4.x * (s3.x + v3.x));
    hn.y = tanhf(s1.y + v1.y + r4.y * (s2.y + v2.y) + z4.y * (s3.y + v3.y));
    hn.z = tanhf(s1.z + v1.z + r4.z * (s2.z + v2.z) + z4.z * (s3.z + v3.z));
    hn.w = tanhf(s1.w + v1.w + r4.w * (s2.w + v2.w) + z4.w * (s3.w + v3.w));
    h1.x = n4.x * hn.x + (1.f - n4.x) * h0v.x;
    h1.y = n4.y * hn.y + (1.f - n4.y) * h0v.y;
    h1.z = n4.z * hn.z + (1.f - n4.z) * h0v.z;
    h1.w = n4.w * hn.w + (1.f - n4.w) * h0v.w;
    *(float4*)(out + (size_t)b * HH + h) = h1;
    *(float4*)(o_row + h) = h1;
}

extern "C" void kernel_launch(void* const* d_in, const int* in_sizes, int n_in,
                              void* d_out, int out_size, void* d_ws, size_t ws_size,
                              hipStream_t stream) {
    const float* input_ = (const float*)d_in[0];
    const float* h0 = (const float*)d_in[1];
    const float* mem = (const float*)d_in[2];
    const float* last_usage = (const float*)d_in[3];
    const float* u1 = (const float*)d_in[4];
    const float* u2 = (const float*)d_in[5];
    const float* W_ih = (const float*)d_in[6];
    const float* W_hh = (const float*)d_in[7];
    const float* W_rh = (const float*)d_in[8];
    const float* W_s1 = (const float*)d_in[9];
    const float* W_s2 = (const float*)d_in[10];
    const float* W_s3 = (const float*)d_in[11];
    const float* bias = (const float*)d_in[12];
    const float* W_im = (const float*)d_in[13];
    const float* W_hm = (const float*)d_in[14];
    const float* fc1_w = (const float*)d_in[15];
    const float* fc1_b = (const float*)d_in[16];
    const float* W_im1 = (const float*)d_in[17];
    const float* W_hm1 = (const float*)d_in[18];
    const float* W_mm1 = (const float*)d_in[19];
    const float* bias_m1 = (const float*)d_in[20];
    const float* bias_1 = (const float*)d_in[21];
    const float* bias_2 = (const float*)d_in[22];
    const float* bias_3 = (const float*)d_in[23];
    float* out = (float*)d_out;

    float* ws = (float*)d_ws;
    float* sg1 = ws;                        // 65536
    float* sg2 = sg1 + 65536;               // 65536
    float* wbp = sg2 + 65536;               // 6 * 786432
    float* Sp = wbp + 6 * 786432;           // 2 * 786432
    unsigned short* Abf = (unsigned short*)(Sp + 2 * 786432);  // 786432 bf16
    unsigned short* WtG = Abf + 786432;     // 9437184 bf16
    unsigned short* WtS = WtG + 9437184;    // 3145728 bf16
    float* Pbuf = (float*)(WtS + 3145728);  // 65536*128 fp32 = 33.5 MB

    k_pgemm_cvt<<<512 + 3072, 256, 0, stream>>>(mem, fc1_w, W_ih, W_hh, W_rh,
                                                W_s1, W_s2, W_s3, WtG, WtS, Pbuf);
    k_score1<<<BB, 1024, 0, stream>>>(input_, h0, W_im, W_hm, fc1_w, fc1_b,
                                      Pbuf, last_usage, u1, Abf, sg1);
    k_sel_score2<<<BB, 1024, 0, stream>>>(sg1, mem, h0, input_, W_im1, W_hm1, W_mm1, bias_m1,
                                          fc1_w, fc1_b, Pbuf, last_usage, u2, Abf, sg2);
    k_gemm<<<384, 256, 0, stream>>>(Abf, WtG, WtS, wbp, Sp);
    k_final<<<BB, 256, 0, stream>>>(sg2, mem, wbp, Sp, h0, bias, bias_1, bias_2, bias_3, out);
}

// Round 10
// 575.198 us; speedup vs baseline: 1.0445x; 1.0078x over previous
//
#include <hip/hip_runtime.h>

#define BB 256
#define HH 1024
#define MM 256
#define HS 128
#define NH 129  // HS+1

typedef __attribute__((ext_vector_type(8))) short short8;
typedef __attribute__((ext_vector_type(4))) float float4v;

__device__ __forceinline__ float sigmoidf_(float x) { return 1.0f / (1.0f + expf(-x)); }
__device__ __forceinline__ float gumbelf_(float u) { return -logf(1e-20f - logf(1e-20f + u)); }

__device__ __forceinline__ unsigned short f2bf(float x) {
    union { float f; unsigned u; } c; c.f = x;
    unsigned u = c.u;
    return (unsigned short)((u + 0x7FFFu + ((u >> 16) & 1u)) >> 16);
}
__device__ __forceinline__ float bf2f(unsigned s) {
    union { unsigned u; float f; } c; c.u = s << 16; return c.f;
}

// ---------------------------------------------------------------- scoring from bf16 P
// thread handles row m = wave*16 + (lane>>2), j-chunk q4 = lane&3 (32 j's each).
// m==0 overridden by exact fp32 dot(h0,sv) on wave 15 (bitwise round-2..9 order).
__device__ __forceinline__ void score_from_P(const unsigned short* __restrict__ P,
                                             const float* __restrict__ sj,
                                             const float* __restrict__ sv,
                                             const float* __restrict__ h0row,
                                             float cb, float hf,
                                             const float* __restrict__ last_usage,
                                             const float* __restrict__ u,
                                             float* __restrict__ sg_out,
                                             int b, int t) {
    int wave = t >> 6, lane = t & 63;
    int mrow = wave * 16 + (lane >> 2);
    int q4 = lane & 3;
    const unsigned short* Prow = P + ((size_t)b * MM + mrow) * HS + q4 * 32;
    float p = 0.f;
#pragma unroll
    for (int g = 0; g < 4; ++g) {
        uint4 pk = *(const uint4*)(Prow + g * 8);
        float4 s0 = *(const float4*)(sj + q4 * 32 + g * 8);
        float4 s1 = *(const float4*)(sj + q4 * 32 + g * 8 + 4);
        p += bf2f(pk.x & 0xffffu) * s0.x + bf2f(pk.x >> 16) * s0.y +
             bf2f(pk.y & 0xffffu) * s0.z + bf2f(pk.y >> 16) * s0.w;
        p += bf2f(pk.z & 0xffffu) * s1.x + bf2f(pk.z >> 16) * s1.y +
             bf2f(pk.w & 0xffffu) * s1.z + bf2f(pk.w >> 16) * s1.w;
    }
    p += __shfl_down(p, 2, 64);
    p += __shfl_down(p, 1, 64);
    if (q4 == 0 && mrow != 0) {
        int mb = b * MM + mrow;
        sg_out[mb] = p + cb + hf * sigmoidf_(last_usage[mb]) + gumbelf_(u[mb]);
    }
    if (wave == 15) {  // exact fp32 row 0 (mem_eff[b,0] = h0)
        float q = 0.f;
#pragma unroll
        for (int it = 0; it < 4; ++it) {
            float4 mv = *(const float4*)(h0row + it * 256 + lane * 4);
            float4 rv = *(const float4*)(sv + it * 256 + lane * 4);
            q += mv.x * rv.x + mv.y * rv.y + mv.z * rv.z + mv.w * rv.w;
        }
        for (int off = 32; off > 0; off >>= 1) q += __shfl_down(q, off, 64);
        if (lane == 0) {
            int mb = b * MM;
            sg_out[mb] = q + cb + hf * sigmoidf_(last_usage[mb]) + gumbelf_(u[mb]);
        }
    }
}

// ---------------------------------------------------------------- 1024-thread GEMM unit
// C(128x128) = A(128x512) * B(128x512)^T, 16 waves in 4x4 grid, 32x32 per wave.
__device__ __forceinline__ void gemm_unit1024(const unsigned short* __restrict__ Ap,
                                              const unsigned short* __restrict__ Bp,
                                              int bstr, int m0, int ncol0,
                                              float* __restrict__ pout,
                                              unsigned short* As, unsigned short* Bs) {
    int t = threadIdx.x;
    int wave = t >> 6, lane = t & 63;
    int wm = wave >> 2, wn = wave & 3;
    int q = lane >> 4, lm = lane & 15;
    float4v acc[2][2];
    for (int i = 0; i < 2; ++i)
        for (int j = 0; j < 2; ++j)
            acc[i][j] = (float4v){0.f, 0.f, 0.f, 0.f};
    int row = t >> 3, cg = t & 7;
    for (int kt = 0; kt < 512; kt += 64) {
        *(uint4*)&As[row * 72 + cg * 8] =
            *(const uint4*)(Ap + (size_t)(m0 + row) * 3072 + kt + cg * 8);
        *(uint4*)&Bs[row * 72 + cg * 8] =
            *(const uint4*)(Bp + (size_t)row * bstr + kt + cg * 8);
        __syncthreads();
        for (int ks = 0; ks < 64; ks += 32) {
            short8 av[2], bv[2];
            for (int i = 0; i < 2; ++i)
                av[i] = *(const short8*)&As[(wm * 32 + i * 16 + lm) * 72 + ks + q * 8];
            for (int j = 0; j < 2; ++j)
                bv[j] = *(const short8*)&Bs[(wn * 32 + j * 16 + lm) * 72 + ks + q * 8];
            for (int i = 0; i < 2; ++i)
                for (int j = 0; j < 2; ++j)
                    acc[i][j] = __builtin_amdgcn_mfma_f32_16x16x32_bf16(av[i], bv[j], acc[i][j], 0, 0, 0);
        }
        __syncthreads();
    }
    for (int i = 0; i < 2; ++i)
        for (int j = 0; j < 2; ++j) {
            int n = ncol0 + wn * 32 + j * 16 + lm;
            for (int reg = 0; reg < 4; ++reg) {
                int m = m0 + wm * 32 + i * 16 + q * 4 + reg;
                pout[(size_t)m * 3072 + n] = acc[i][j][reg];
            }
        }
}

// unit decode (same numbering as rounds 5-9)
__device__ __forceinline__ void decode_unit(int unit,
                                            const unsigned short* Abf,
                                            const unsigned short* WtG,
                                            const unsigned short* WtS,
                                            float* wbp, float* Sp,
                                            const unsigned short** Ap,
                                            const unsigned short** Bp,
                                            int* bstr, int* ncol0, float** pout) {
    if (unit < 144) {
        int nt = unit % 24, kidx = unit / 24;
        int ksel = kidx >> 1, khalf = kidx & 1;
        *ncol0 = nt * 128;
        *Bp = WtG + (size_t)(nt * 128) * 3072 + ksel * 1024 + khalf * 512;
        *bstr = 3072;
        *Ap = Abf + ksel * 1024 + khalf * 512;
        *pout = wbp + (size_t)kidx * 786432;
    } else {
        int su = unit - 144;
        int seg = su / 16, rem = su % 16;
        int khalf = rem >> 3, nts = rem & 7;
        *ncol0 = seg * 1024 + nts * 128;
        *Bp = WtS + (size_t)seg * 1048576 + (size_t)(nts * 128) * 1024 + khalf * 512;
        *bstr = 1024;
        *Ap = Abf + seg * 1024 + khalf * 512;
        *pout = Sp + (size_t)khalf * 786432;
    }
}

// ---------------------------------------------------------------- L1: P-GEMM (bx<512) + wt cvt (512..3583) + act cvt (3584..3711)
__global__ __launch_bounds__(256) void k_pgemm_cvt(const float* __restrict__ mem,
                                                   const float* __restrict__ fc1_w,
                                                   const float* __restrict__ input_,
                                                   const float* __restrict__ h0,
                                                   const float* __restrict__ W_ih,
                                                   const float* __restrict__ W_hh,
                                                   const float* __restrict__ W_rh,
                                                   const float* __restrict__ W_s1,
                                                   const float* __restrict__ W_s2,
                                                   const float* __restrict__ W_s3,
                                                   unsigned short* __restrict__ WtG,
                                                   unsigned short* __restrict__ WtS,
                                                   unsigned short* __restrict__ Abf,
                                                   unsigned short* __restrict__ P) {
    __shared__ __align__(16) unsigned char smem[36864];
    int bx = blockIdx.x, t = threadIdx.x;
    if (bx >= 3584) {
        // ---- act convert: input_/h0 -> Abf[:,0:2048]
        int tile = bx - 3584;
        for (int g = 0; g < 4; ++g) {
            int e4 = tile * 1024 + g * 256 + t;
            int base = e4 * 4;
            const float* src;
            unsigned short* dst;
            if (base < 262144) {
                int b = base >> 10, pos = base & 1023;
                src = input_ + (size_t)b * HH + pos;
                dst = Abf + (size_t)b * 3072 + pos;
            } else {
                int e2 = base - 262144;
                int b = e2 >> 10, pos = e2 & 1023;
                src = h0 + (size_t)b * HH + pos;
                dst = Abf + (size_t)b * 3072 + 1024 + pos;
            }
            float4 v = *(const float4*)src;
            ushort4 o; o.x = f2bf(v.x); o.y = f2bf(v.y); o.z = f2bf(v.z); o.w = f2bf(v.w);
            *(ushort4*)dst = o;
        }
        return;
    }
    if (bx >= 512) {
        // ---- weight convert/transpose tile
        unsigned short (*T)[66] = (unsigned short (*)[66])smem;
        int tile = bx - 512;               // 0..3071
        const float* src;
        unsigned short* dst;
        int k0, n0, sstr, dstr, krel;
        if (tile < 2304) {
            int kt = tile / 48, nt = tile % 48;
            k0 = kt * 64; n0 = nt * 64;
            src = (k0 < 1024) ? W_ih : (k0 < 2048) ? W_hh : W_rh;
            krel = k0 & 1023;
            dst = WtG; sstr = 3072; dstr = 3072;
        } else {
            int r = tile - 2304;
            int seg = r >> 8;
            int rem = r & 255;
            int kt = rem >> 4, nt = rem & 15;
            k0 = kt * 64; n0 = nt * 64;
            src = (seg == 0) ? W_s1 : (seg == 1) ? W_s2 : W_s3;
            krel = k0;
            dst = WtS + (size_t)seg * 1048576; sstr = 1024; dstr = 1024;
        }
        for (int i = 0; i < 4; ++i) {
            int e = i * 256 + t;
            int kk = e >> 4, nn0 = (e & 15) * 4;
            float4 v = *(const float4*)(src + (size_t)(krel + kk) * sstr + n0 + nn0);
            T[nn0 + 0][kk] = f2bf(v.x);
            T[nn0 + 1][kk] = f2bf(v.y);
            T[nn0 + 2][kk] = f2bf(v.z);
            T[nn0 + 3][kk] = f2bf(v.w);
        }
        __syncthreads();
        for (int i = 0; i < 8; ++i) {
            int e = i * 256 + t;
            int nn = e >> 5, kk2 = (e & 31) * 2;
            unsigned val = (unsigned)T[nn][kk2] | ((unsigned)T[nn][kk2 + 1] << 16);
            *(unsigned*)(dst + (size_t)(n0 + nn) * dstr + k0 + kk2) = val;
        }
        return;
    }
    // ---- P-GEMM: 128 rows x 128 cols, K = 1024, on-the-fly fp32->bf16, bf16 out
    unsigned short* As = (unsigned short*)smem;          // 128*72
    unsigned short* Bs = As + 128 * 72;                  // 128*72
    int m0 = bx * 128;
    const float* Asrc = mem + (size_t)m0 * 1024;

    int wave = t >> 6, lane = t & 63;
    int wm = wave >> 1, wn = wave & 1;
    int q = lane >> 4, lm = lane & 15;

    float4v acc[4][4];
    for (int i = 0; i < 4; ++i)
        for (int j = 0; j < 4; ++j)
            acc[i][j] = (float4v){0.f, 0.f, 0.f, 0.f};

    for (int kt = 0; kt < 1024; kt += 64) {
        for (int g = 0; g < 4; ++g) {
            int gi = g * 256 + t;          // 0..1023
            int row = gi >> 3, seg = gi & 7;
            const float* sa = Asrc + (size_t)row * 1024 + kt + seg * 8;
            float4 f0 = *(const float4*)sa;
            float4 f1 = *(const float4*)(sa + 4);
            uint4 pk;
            pk.x = (unsigned)f2bf(f0.x) | ((unsigned)f2bf(f0.y) << 16);
            pk.y = (unsigned)f2bf(f0.z) | ((unsigned)f2bf(f0.w) << 16);
            pk.z = (unsigned)f2bf(f1.x) | ((unsigned)f2bf(f1.y) << 16);
            pk.w = (unsigned)f2bf(f1.z) | ((unsigned)f2bf(f1.w) << 16);
            *(uint4*)&As[row * 72 + seg * 8] = pk;
            const float* sb = fc1_w + (size_t)row * 1024 + kt + seg * 8;
            float4 g0 = *(const float4*)sb;
            float4 g1 = *(const float4*)(sb + 4);
            uint4 qk;
            qk.x = (unsigned)f2bf(g0.x) | ((unsigned)f2bf(g0.y) << 16);
            qk.y = (unsigned)f2bf(g0.z) | ((unsigned)f2bf(g0.w) << 16);
            qk.z = (unsigned)f2bf(g1.x) | ((unsigned)f2bf(g1.y) << 16);
            qk.w = (unsigned)f2bf(g1.z) | ((unsigned)f2bf(g1.w) << 16);
            *(uint4*)&Bs[row * 72 + seg * 8] = qk;
        }
        __syncthreads();
        for (int ks = 0; ks < 64; ks += 32) {
            short8 av[4], bv[4];
            for (int i = 0; i < 4; ++i)
                av[i] = *(const short8*)&As[(wm * 64 + i * 16 + lm) * 72 + ks + q * 8];
            for (int j = 0; j < 4; ++j)
                bv[j] = *(const short8*)&Bs[(wn * 64 + j * 16 + lm) * 72 + ks + q * 8];
            for (int i = 0; i < 4; ++i)
                for (int j = 0; j < 4; ++j)
                    acc[i][j] = __builtin_amdgcn_mfma_f32_16x16x32_bf16(av[i], bv[j], acc[i][j], 0, 0, 0);
        }
        __syncthreads();
    }

    for (int i = 0; i < 4; ++i)
        for (int j = 0; j < 4; ++j) {
            int n = wn * 64 + j * 16 + lm;
            for (int reg = 0; reg < 4; ++reg) {
                int m = m0 + wm * 64 + i * 16 + q * 4 + reg;
                P[(size_t)m * HS + n] = f2bf(acc[i][j][reg]);
            }
        }
}

// ---------------------------------------------------------------- L2: heads + project + scores1 (from P)
__global__ __launch_bounds__(1024) void k_score1(const float* __restrict__ input_,
                                                 const float* __restrict__ h0,
                                                 const float* __restrict__ W_im,
                                                 const float* __restrict__ W_hm,
                                                 const float* __restrict__ fc1_w,
                                                 const float* __restrict__ fc1_b,
                                                 const unsigned short* __restrict__ P,
                                                 const float* __restrict__ last_usage,
                                                 const float* __restrict__ u1,
                                                 float* __restrict__ sg_out) {
    __shared__ __align__(16) float sx[HH];
    __shared__ __align__(16) float sh[HH];
    __shared__ __align__(16) float sv[HH];
    __shared__ float red[8][128];
    __shared__ float red2[8];
    __shared__ __align__(16) float sj[132];
    __shared__ float scb;
    int b = blockIdx.x, t = threadIdx.x;
    if (t < 256) {
        *(float4*)(sx + t * 4) = *(const float4*)(input_ + (size_t)b * HH + t * 4);
    } else if (t < 512) {
        int tt = t - 256;
        *(float4*)(sh + tt * 4) = *(const float4*)(h0 + (size_t)b * HH + tt * 4);
    }
    __syncthreads();
    {   // read_head GEMV: j = t&127, 8-way K-split
        int j = t & 127, ks = t >> 7;
        int hb = ks * 128;
        float p = 0.f;
#pragma unroll 8
        for (int h = hb; h < hb + 128; ++h)
            p += sx[h] * W_im[h * NH + j] + sh[h] * W_hm[h * NH + j];
        red[ks][j] = p;
        if (t >= 1016) {
            int k2 = t - 1016;
            int hb2 = k2 * 128;
            float q = 0.f;
#pragma unroll 8
            for (int h = hb2; h < hb2 + 128; ++h)
                q += sx[h] * W_im[h * NH + 128] + sh[h] * W_hm[h * NH + 128];
            red2[k2] = q;
        }
    }
    __syncthreads();
    if (t < 128) {
        float s = 0.f;
        for (int k = 0; k < 8; ++k) s += red[k][t];
        sj[t] = tanhf(s);
    } else if (t == 128) {
        float s = 0.f;
        for (int k = 0; k < 8; ++k) s += red2[k];
        sj[128] = tanhf(s);
    }
    __syncthreads();
    {   // v projection
        float acc = 0.f;
#pragma unroll 4
        for (int j = 0; j < HS; ++j) acc += sj[j] * fc1_w[(size_t)j * HH + t];
        sv[t] = acc;
    }
    if (t < 64) {
        float p = sj[t] * fc1_b[t] + sj[t + 64] * fc1_b[t + 64];
        for (int off = 32; off > 0; off >>= 1) p += __shfl_down(p, off, 64);
        if (t == 0) scb = p;
    }
    __syncthreads();
    score_from_P(P, sj, sv, h0 + (size_t)b * HH, scb, sj[128], last_usage, u1, sg_out, b, t);
}

// ---------------------------------------------------------------- L3: sel1+head1+scores2 (bx<256) + gemm part1 (bx>=256)
__global__ __launch_bounds__(1024) void k_sel_gemm(const float* __restrict__ sg1,
                                                   const float* __restrict__ mem,
                                                   const float* __restrict__ h0,
                                                   const float* __restrict__ input_,
                                                   const float* __restrict__ W_im1,
                                                   const float* __restrict__ W_hm1,
                                                   const float* __restrict__ W_mm1,
                                                   const float* __restrict__ bias_m1,
                                                   const float* __restrict__ fc1_w,
                                                   const float* __restrict__ fc1_b,
                                                   const unsigned short* __restrict__ P,
                                                   const float* __restrict__ last_usage,
                                                   const float* __restrict__ u2,
                                                   unsigned short* __restrict__ Abf,
                                                   const unsigned short* __restrict__ WtG,
                                                   const unsigned short* __restrict__ WtS,
                                                   float* __restrict__ wbp,
                                                   float* __restrict__ Sp,
                                                   float* __restrict__ sg_out) {
    __shared__ __align__(16) unsigned char smem[36864];
    int bx = blockIdx.x, t = threadIdx.x;
    if (bx >= 256) {
        int g = bx - 256;                  // 0..255
        int mtile = g & 1, idx = g >> 1;   // idx 0..127
        int unit = (idx < 96) ? idx : 144 + (idx - 96);
        const unsigned short *Ap, *Bp;
        int bstr, ncol0;
        float* pout;
        decode_unit(unit, Abf, WtG, WtS, wbp, Sp, &Ap, &Bp, &bstr, &ncol0, &pout);
        unsigned short* As = (unsigned short*)smem;
        unsigned short* Bs = As + 128 * 72;
        gemm_unit1024(Ap, Bp, bstr, mtile * 128, ncol0, pout, As, Bs);
        return;
    }
    // ---- sel1 + head1 + scores pass 2
    float* sx = (float*)smem;              // 1024
    float* sh = sx + 1024;
    float* se = sh + 1024;
    float* sv = se + 1024;
    float* svals = sv + 1024;              // 256
    int* sidx = (int*)(svals + 256);       // 256
    float* red = (float*)(sidx + 256);     // 8*128
    float* red2 = red + 1024;              // 8
    float* sj = red2 + 8;                  // 132
    float* scb = sj + 132;                 // 1
    int b = bx;
    if (t < 256) {
        svals[t] = sg1[b * MM + t];
        sidx[t] = t;
    }
    __syncthreads();
    for (int s = 128; s > 0; s >>= 1) {
        if (t < s) {
            if (svals[t + s] > svals[t]) { svals[t] = svals[t + s]; sidx[t] = sidx[t + s]; }
        }
        __syncthreads();
    }
    int mstar = sidx[0];
    const float* erow = (mstar == 0) ? (h0 + (size_t)b * HH) : (mem + ((size_t)(b * MM + mstar)) * HH);
    if (t < 256) {
        float4 v = *(const float4*)(erow + t * 4);
        *(float4*)(se + t * 4) = v;
        ushort4 o; o.x = f2bf(v.x); o.y = f2bf(v.y); o.z = f2bf(v.z); o.w = f2bf(v.w);
        *(ushort4*)(Abf + (size_t)b * 3072 + 2048 + t * 4) = o;
    } else if (t < 512) {
        int tt = t - 256;
        *(float4*)(sx + tt * 4) = *(const float4*)(input_ + (size_t)b * HH + tt * 4);
    } else if (t < 768) {
        int tt = t - 512;
        *(float4*)(sh + tt * 4) = *(const float4*)(h0 + (size_t)b * HH + tt * 4);
    }
    __syncthreads();
    {
        int j = t & 127, ks = t >> 7;
        int hb = ks * 128;
        float p = 0.f;
#pragma unroll 4
        for (int h = hb; h < hb + 128; ++h)
            p += sx[h] * W_im1[h * NH + j] + sh[h] * W_hm1[h * NH + j] + se[h] * W_mm1[h * NH + j];
        red[ks * 128 + j] = p;
        if (t >= 1016) {
            int k2 = t - 1016;
            int hb2 = k2 * 128;
            float q = 0.f;
#pragma unroll 4
            for (int h = hb2; h < hb2 + 128; ++h)
                q += sx[h] * W_im1[h * NH + 128] + sh[h] * W_hm1[h * NH + 128] + se[h] * W_mm1[h * NH + 128];
            red2[k2] = q;
        }
    }
    __syncthreads();
    if (t < 128) {
        float s = bias_m1[t];
        for (int k = 0; k < 8; ++k) s += red[k * 128 + t];
        sj[t] = tanhf(s);
    } else if (t == 128) {
        float s = bias_m1[128];
        for (int k = 0; k < 8; ++k) s += red2[k];
        sj[128] = tanhf(s);
    }
    __syncthreads();
    {
        float acc = 0.f;
#pragma unroll 4
        for (int j = 0; j < HS; ++j) acc += sj[j] * fc1_w[(size_t)j * HH + t];
        sv[t] = acc;
    }
    if (t < 64) {
        float p = sj[t] * fc1_b[t] + sj[t + 64] * fc1_b[t + 64];
        for (int off = 32; off > 0; off >>= 1) p += __shfl_down(p, off, 64);
        if (t == 0) *scb = p;
    }
    __syncthreads();
    score_from_P(P, sj, sv, h0 + (size_t)b * HH, *scb, sj[128], last_usage, u2, sg_out, b, t);
}

// ---------------------------------------------------------------- L4: gemm part2 (entry-dependent units)
__global__ __launch_bounds__(1024) void k_gemm2(const unsigned short* __restrict__ Abf,
                                                const unsigned short* __restrict__ WtG,
                                                const unsigned short* __restrict__ WtS,
                                                float* __restrict__ wbp,
                                                float* __restrict__ Sp) {
    __shared__ __align__(16) unsigned char smem[36864];
    int bx = blockIdx.x;                   // 0..127
    int mtile = bx & 1, idx = bx >> 1;     // idx 0..63
    int unit = (idx < 48) ? 96 + idx : 176 + (idx - 48);
    const unsigned short *Ap, *Bp;
    int bstr, ncol0;
    float* pout;
    decode_unit(unit, Abf, WtG, WtS, wbp, Sp, &Ap, &Bp, &bstr, &ncol0, &pout);
    unsigned short* As = (unsigned short*)smem;
    unsigned short* Bs = As + 128 * 72;
    gemm_unit1024(Ap, Bp, bstr, mtile * 128, ncol0, pout, As, Bs);
}

// ---------------------------------------------------------------- L5: final (fused sel2 + GRU epilogue)
__global__ __launch_bounds__(256) void k_final(const float* __restrict__ sg2,
                                               const float* __restrict__ mem,
                                               const float* __restrict__ wbp,
                                               const float* __restrict__ Sp,
                                               const float* __restrict__ h0,
                                               const float* __restrict__ bias,
                                               const float* __restrict__ b1,
                                               const float* __restrict__ b2,
                                               const float* __restrict__ b3,
                                               float* __restrict__ out) {
    __shared__ float svals[256];
    __shared__ int sidx[256];
    int b = blockIdx.x, t = threadIdx.x;
    svals[t] = sg2[b * MM + t];
    sidx[t] = t;
    __syncthreads();
    for (int s = 128; s > 0; s >>= 1) {
        if (t < s) {
            if (svals[t + s] > svals[t]) { svals[t] = svals[t + s]; sidx[t] = sidx[t + s]; }
        }
        __syncthreads();
    }
    int mstar = sidx[0];
    const float* erow = (mstar == 0) ? (h0 + (size_t)b * HH) : (mem + ((size_t)(b * MM + mstar)) * HH);
    float* o_row = out + (size_t)BB * HH + (size_t)b * 2 * HH;
    {
        int hb = t * 4;
        *(float4*)(o_row + HH + hb) = *(const float4*)(erow + hb);
    }
    int h = t * 4;
    size_t base = (size_t)b * 3072;
    float4 wsum[3];
#pragma unroll
    for (int g = 0; g < 3; ++g) {
        float4 a = make_float4(0.f, 0.f, 0.f, 0.f);
#pragma unroll
        for (int p = 0; p < 6; ++p) {
            float4 w = *(const float4*)(wbp + (size_t)p * 786432 + base + g * 1024 + h);
            a.x += w.x; a.y += w.y; a.z += w.z; a.w += w.w;
        }
        wsum[g] = a;
    }
    float4 bi0 = *(const float4*)(bias + h);
    float4 bi1 = *(const float4*)(bias + 1024 + h);
    float4 bi2 = *(const float4*)(bias + 2048 + h);
    float4 r4 = make_float4(sigmoidf_(wsum[0].x + bi0.x), sigmoidf_(wsum[0].y + bi0.y),
                            sigmoidf_(wsum[0].z + bi0.z), sigmoidf_(wsum[0].w + bi0.w));
    float4 z4 = make_float4(sigmoidf_(wsum[1].x + bi1.x), sigmoidf_(wsum[1].y + bi1.y),
                            sigmoidf_(wsum[1].z + bi1.z), sigmoidf_(wsum[1].w + bi1.w));
    float4 n4 = make_float4(sigmoidf_(wsum[2].x + bi2.x), sigmoidf_(wsum[2].y + bi2.y),
                            sigmoidf_(wsum[2].z + bi2.z), sigmoidf_(wsum[2].w + bi2.w));
    float4 s1, s2, s3;
    {
        float4 a0 = *(const float4*)(Sp + base + h);
        float4 a1 = *(const float4*)(Sp + 786432 + base + h);
        s1 = make_float4(a0.x + a1.x, a0.y + a1.y, a0.z + a1.z, a0.w + a1.w);
        a0 = *(const float4*)(Sp + base + 1024 + h);
        a1 = *(const float4*)(Sp + 786432 + base + 1024 + h);
        s2 = make_float4(a0.x + a1.x, a0.y + a1.y, a0.z + a1.z, a0.w + a1.w);
        a0 = *(const float4*)(Sp + base + 2048 + h);
        a1 = *(const float4*)(Sp + 786432 + base + 2048 + h);
        s3 = make_float4(a0.x + a1.x, a0.y + a1.y, a0.z + a1.z, a0.w + a1.w);
    }
    float4 v1 = *(const float4*)(b1 + h);
    float4 v2 = *(const float4*)(b2 + h);
    float4 v3 = *(const float4*)(b3 + h);
    float4 h0v = *(const float4*)(h0 + (size_t)b * HH + h);
    float4 hn, h1;
    hn.x = tanhf(s1.x + v1.x + r4.x * (s2.x + v2.x) + z4.x * (s3.x + v3.x));
    hn.y = tanhf(s1.y + v1.y + r4.y * (s2.y + v2.y) + z4.y * (s3.y + v3.y));
    hn.z = tanhf(s1.z + v1.z + r4.z * (s2.z + v2.z) + z4.z * (s3.z + v3.z));
    hn.w = tanhf(s1.w + v1.w + r4.w * (s2.w + v2.w) + z4.w * (s3.w + v3.w));
    h1.x = n4.x * hn.x + (1.f - n4.x) * h0v.x;
    h1.y = n4.y * hn.y + (1.f - n4.y) * h0v.y;
    h1.z = n4.z * hn.z + (1.f - n4.z) * h0v.z;
    h1.w = n4.w * hn.w + (1.f - n4.w) * h0v.w;
    *(float4*)(out + (size_t)b * HH + h) = h1;
    *(float4*)(o_row + h) = h1;
}

extern "C" void kernel_launch(void* const* d_in, const int* in_sizes, int n_in,
                              void* d_out, int out_size, void* d_ws, size_t ws_size,
                              hipStream_t stream) {
    const float* input_ = (const float*)d_in[0];
    const float* h0 = (const float*)d_in[1];
    const float* mem = (const float*)d_in[2];
    const float* last_usage = (const float*)d_in[3];
    const float* u1 = (const float*)d_in[4];
    const float* u2 = (const float*)d_in[5];
    const float* W_ih = (const float*)d_in[6];
    const float* W_hh = (const float*)d_in[7];
    const float* W_rh = (const float*)d_in[8];
    const float* W_s1 = (const float*)d_in[9];
    const float* W_s2 = (const float*)d_in[10];
    const float* W_s3 = (const float*)d_in[11];
    const float* bias = (const float*)d_in[12];
    const float* W_im = (const float*)d_in[13];
    const float* W_hm = (const float*)d_in[14];
    const float* fc1_w = (const float*)d_in[15];
    const float* fc1_b = (const float*)d_in[16];
    const float* W_im1 = (const float*)d_in[17];
    const float* W_hm1 = (const float*)d_in[18];
    const float* W_mm1 = (const float*)d_in[19];
    const float* bias_m1 = (const float*)d_in[20];
    const float* bias_1 = (const float*)d_in[21];
    const float* bias_2 = (const float*)d_in[22];
    const float* bias_3 = (const float*)d_in[23];
    float* out = (float*)d_out;

    float* ws = (float*)d_ws;
    float* sg1 = ws;                        // 65536
    float* sg2 = sg1 + 65536;               // 65536
    float* wbp = sg2 + 65536;               // 6 * 786432
    float* Sp = wbp + 6 * 786432;           // 2 * 786432
    unsigned short* Abf = (unsigned short*)(Sp + 2 * 786432);  // 786432 bf16
    unsigned short* WtG = Abf + 786432;     // 9437184 bf16
    unsigned short* WtS = WtG + 9437184;    // 3145728 bf16
    unsigned short* Pbuf = WtS + 3145728;   // 65536*128 bf16 = 16.7 MB

    k_pgemm_cvt<<<3712, 256, 0, stream>>>(mem, fc1_w, input_, h0, W_ih, W_hh, W_rh,
                                          W_s1, W_s2, W_s3, WtG, WtS, Abf, Pbuf);
    k_score1<<<BB, 1024, 0, stream>>>(input_, h0, W_im, W_hm, fc1_w, fc1_b,
                                      Pbuf, last_usage, u1, sg1);
    k_sel_gemm<<<512, 1024, 0, stream>>>(sg1, mem, h0, input_, W_im1, W_hm1, W_mm1, bias_m1,
                                         fc1_w, fc1_b, Pbuf, last_usage, u2,
                                         Abf, WtG, WtS, wbp, Sp, sg2);
    k_gemm2<<<128, 1024, 0, stream>>>(Abf, WtG, WtS, wbp, Sp);
    k_final<<<BB, 256, 0, stream>>>(sg2, mem, wbp, Sp, h0, bias, bias_1, bias_2, bias_3, out);
}